// Round 9
// baseline (253.578 us; speedup 1.0000x reference)
//
#include <hip/hip_runtime.h>
#include <hip/hip_bf16.h>
#include <hip/hip_fp16.h>
#include <type_traits>

constexpr int BB = 4;
constexpr int CC = 512;
constexpr int HH = 4096;
constexpr int IC = 256;

typedef _Float16 f16x8v __attribute__((ext_vector_type(8)));
typedef __bf16   bf16x8v __attribute__((ext_vector_type(8)));
typedef float    f32x4v __attribute__((ext_vector_type(4)));

__device__ __forceinline__ void gll16(const void* g, void* l) {
  __builtin_amdgcn_global_load_lds(
      (const __attribute__((address_space(1))) unsigned int*)g,
      (__attribute__((address_space(3))) unsigned int*)l, 16, 0, 0);
}

__device__ __forceinline__ f32x4v mfma16(f16x8v a, f16x8v b, f32x4v c) {
  return __builtin_amdgcn_mfma_f32_16x16x32_f16(a, b, c, 0, 0, 0);
}
__device__ __forceinline__ f32x4v mfma16(bf16x8v a, bf16x8v b, f32x4v c) {
  return __builtin_amdgcn_mfma_f32_16x16x32_bf16(a, b, c, 0, 0, 0);
}

__device__ __forceinline__ unsigned short hbits(float f) {
  __half h = __float2half(f);
  unsigned short b; __builtin_memcpy(&b, &h, 2); return b;
}
__device__ __forceinline__ unsigned short bbits(float f) {
  __hip_bfloat16 h = __float2bfloat16(f);
  unsigned short b; __builtin_memcpy(&b, &h, 2); return b;
}

// ---------------------------------------------------------------------------
// 128x128-tile B^T GEMM (ROUND-4 PROVEN core: BK=64 + chunk-XOR staging
// swizzle, bank conflicts 0, VGPR 80, LDS 32KB).
// Failed levers (do not retry): BK=128 (r5: occupancy halves), LDS-staged
// MODE2 epilogue (r6: adds issue work), no-LDS direct fragments (r7:
// scattered per-lane loads, 139us), swapped packed epilogue (r1: WRITE_SIZE
// +50%). Cross-round MODE2 timing variance is ~±10% at fixed code (r4 62.5
// vs r8 74.6, uniform counter dilution) — don't chase it.
// MODE 0: DUAL theta+phi (blockIdx.z>>2 selects B/bias/out). fp16, +bias[n].
// MODE 1: bf16, (v+bias[m])/Z[b,n]  (g proj -> gB [IC,H]; round 9: fuses
//         the old gscale kernel — runs AFTER MODE2 so Z is ready).
// MODE 2: bf16 exp(v); Z[b,n] += column sums   (scores -> E [q,k])
// MODE 3: fp32, +bias[m] + xres; B operand = SUM OF TWO fp16 SPLIT-K
//         PARTIALS (P16 halves) reg-staged with in-register add (round 8
//         proven: kills cvt_ag kernel + agB buffer).
// ---------------------------------------------------------------------------
template <int MODE, int BK>
__launch_bounds__(256)
__global__ void mgemm128(const void* __restrict__ Aall, const void* __restrict__ Ball,
                         const void* __restrict__ Ball2,
                         void* __restrict__ outP, void* __restrict__ out2P,
                         const float* __restrict__ bias, const float* __restrict__ bias2,
                         const float* __restrict__ xres, float* __restrict__ Z,
                         int M, int N, int K,
                         size_t sAb, size_t sBb, size_t sOb) {
  constexpr int CPR = BK / 8;              // 16B chunks per LDS row
  constexpr int XM = (BK >= 64) ? 7 : 0;   // chunk-XOR swizzle mask

  __shared__ __align__(16) unsigned short sA[128 * BK];
  __shared__ __align__(16) unsigned short sB[128 * BK];

  const int zz = blockIdx.z;
  int b, which;
  if constexpr (MODE == 0) { b = zz & (BB - 1); which = zz >> 2; }
  else { b = zz; which = 0; }

  const unsigned short* __restrict__ A = (const unsigned short*)Aall + (size_t)b * sAb;
  const unsigned short* __restrict__ Bm =
      (const unsigned short*)((MODE == 0 && which) ? Ball2 : Ball) + (size_t)b * sBb;
  const float* __restrict__ biasSel = (MODE == 0 && which) ? bias2 : bias;
  void* __restrict__ outSel = (MODE == 0 && which) ? out2P : outP;

  const int t = threadIdx.x;
  const int lane = t & 63;
  const int w = t >> 6;
  const int wm = (w >> 1) << 6;
  const int wn = (w & 1) << 6;
  const int mBase = blockIdx.y * 128;
  const int nBase = blockIdx.x * 128;

  const int fr = lane & 15;
  const int fo = (lane >> 4) << 3;   // 0,8,16,24 shorts within the 32-k slice
  const int fc = fo >> 3;            // 16B sub-chunk index 0..3

  f32x4v acc[4][4] = {};

  for (int k0 = 0; k0 < K; k0 += BK) {
    // stage: 128 rows x BK k per operand = 128*CPR chunks; CPR/2 per thread
#pragma unroll
    for (int p = 0; p < CPR / 2; ++p) {
      const int u = t + (p << 8);
      const int r = u / CPR;
      const int c = u & (CPR - 1);
      const int cs = (c ^ (r & XM)) << 3;
      gll16(A + (size_t)(mBase + r) * K + (k0 + cs), sA + u * 8);
      if constexpr (MODE == 3) {
        // B = P16 half0 + half1 (fp16), reg-staged with vector add; LDS
        // layout identical to the gll16 path (linear dest, pre-XOR'd src).
        const unsigned short* s0 = Bm + (size_t)(nBase + r) * K + (k0 + cs);
        const f16x8v v0 = *(const f16x8v*)s0;
        const f16x8v v1 = *(const f16x8v*)(s0 + (size_t)BB * HH * IC);
        *(f16x8v*)(sB + u * 8) = v0 + v1;
      } else {
        gll16(Bm + (size_t)(nBase + r) * K + (k0 + cs), sB + u * 8);
      }
    }
    __syncthreads();
#pragma unroll
    for (int ks = 0; ks < BK / 32; ++ks) {
      f16x8v af[4], bf[4];
#pragma unroll
      for (int i = 0; i < 4; ++i) {
        const int row = wm + (i << 4) + fr;
        const int phys = ((ks << 2) + fc) ^ (row & XM);
        af[i] = *(const f16x8v*)(sA + row * BK + (phys << 3));
      }
#pragma unroll
      for (int j = 0; j < 4; ++j) {
        const int row = wn + (j << 4) + fr;
        const int phys = ((ks << 2) + fc) ^ (row & XM);
        bf[j] = *(const f16x8v*)(sB + row * BK + (phys << 3));
      }
#pragma unroll
      for (int i = 0; i < 4; ++i)
#pragma unroll
        for (int j = 0; j < 4; ++j)
          acc[i][j] = mfma16(af[i], bf[j], acc[i][j]);
    }
    __syncthreads();
  }

  const int row0 = (lane >> 4) << 2;
  const int col = lane & 15;

  if constexpr (MODE == 2) {
    __hip_bfloat16* __restrict__ outB = (__hip_bfloat16*)outP;
    float csum[4] = {0.f, 0.f, 0.f, 0.f};
#pragma unroll
    for (int i = 0; i < 4; ++i) {
      const int m0 = mBase + wm + (i << 4) + row0;
#pragma unroll
      for (int j = 0; j < 4; ++j) {
        const int n = nBase + wn + (j << 4) + col;
        __hip_bfloat16* dst = outB + (size_t)b * sOb + (size_t)m0 * N + n;
#pragma unroll
        for (int rg = 0; rg < 4; ++rg) {
          const float e = __expf(acc[i][j][rg]);
          dst[(size_t)rg * N] = __float2bfloat16(e);
          csum[j] += e;
        }
      }
    }
#pragma unroll
    for (int j = 0; j < 4; ++j) {
      float s = csum[j];
      s += __shfl_xor(s, 16, 64);
      s += __shfl_xor(s, 32, 64);
      if (lane < 16) {
        const int n = nBase + wn + (j << 4) + col;
        atomicAdd(&Z[(size_t)b * N + n], s);
      }
    }
  } else {
    // MODE1: per-column softmax-denominator reciprocal (n indep. of i/rg)
    float rzv[4];
    if constexpr (MODE == 1) {
#pragma unroll
      for (int j = 0; j < 4; ++j) {
        const int n = nBase + wn + (j << 4) + col;
        rzv[j] = 1.0f / Z[(size_t)b * N + n];
      }
    }
#pragma unroll
    for (int i = 0; i < 4; ++i) {
      const int m0 = mBase + wm + (i << 4) + row0;
#pragma unroll
      for (int j = 0; j < 4; ++j) {
        const int n = nBase + wn + (j << 4) + col;
#pragma unroll
        for (int rg = 0; rg < 4; ++rg) {
          const int m = m0 + rg;
          const float v = acc[i][j][rg];
          if constexpr (MODE == 0) {
            ((__half*)outSel)[(size_t)b * sOb + (size_t)m * N + n] =
                __float2half(v + biasSel[n]);
          } else if constexpr (MODE == 1) {
            ((__hip_bfloat16*)outP)[(size_t)b * sOb + (size_t)m * N + n] =
                __float2bfloat16((v + bias[m]) * rzv[j]);
          } else {
            const size_t o = (size_t)b * sOb + (size_t)m * N + n;
            ((float*)outP)[o] = v + bias[m] + xres[o];
          }
        }
      }
    }
  }
  (void)M;
}

// ---------------------------------------------------------------------------
// ag GEMM v3 (round-3 PROVEN: 74.6 -> ~45us). BK=128 (256B-contiguous E
// reads) + chunk-XOR swizzled LDS, split-K=2, single-buffered.
// Partial tiles -> fp16 packed ushort4 stores into P16[kc][b][q][ic].
// P16 is consumed DIRECTLY by mgemm128<3> (round 8) — no cvt kernel.
// ---------------------------------------------------------------------------
__launch_bounds__(256)
__global__ void mgemm_ag(const __hip_bfloat16* __restrict__ Gall,
                         const __hip_bfloat16* __restrict__ Eall,
                         unsigned short* __restrict__ P16) {
  constexpr int KC = 2048;
  constexpr int BK = 128;
  __shared__ __align__(16) unsigned short sG[256 * BK];  // 64 KB
  __shared__ __align__(16) unsigned short sE[64 * BK];   // 16 KB

  const int b = blockIdx.z;
  const int kc = blockIdx.x;            // 0..1
  const int qBase = blockIdx.y * 64;
  const int k0base = kc * KC;

  const unsigned short* __restrict__ G =
      (const unsigned short*)Gall + (size_t)b * IC * HH;
  const unsigned short* __restrict__ E =
      (const unsigned short*)Eall + (size_t)b * HH * HH;

  const int t = threadIdx.x;
  const int lane = t & 63;
  const int w = t >> 6;
  const int fr = lane & 15;
  const int fo = (lane >> 4) << 3;      // 0,8,16,24 shorts
  const int fc = fo >> 3;               // chunk sub-index 0..3

  f32x4v acc[4][4] = {};

  for (int kk = 0; kk < KC; kk += BK) {
    const int k0 = k0base + kk;
    // stage E first (HBM, long latency): 64 rows x 128k = 1024 chunks
#pragma unroll
    for (int p = 0; p < 4; ++p) {
      const int u = t + (p << 8);
      const int row = u >> 4;
      const int csrc = (u & 15) ^ (row & 7);
      gll16(E + (size_t)(qBase + row) * HH + k0 + (csrc << 3), sE + u * 8);
    }
    // stage G (mostly L2): 256 rows x 128k = 4096 chunks
#pragma unroll
    for (int p = 0; p < 16; ++p) {
      const int u = t + (p << 8);
      const int row = u >> 4;
      const int csrc = (u & 15) ^ (row & 7);
      gll16(G + (size_t)row * HH + k0 + (csrc << 3), sG + u * 8);
    }
    __syncthreads();
#pragma unroll
    for (int ks = 0; ks < 4; ++ks) {
      bf16x8v af[4], bfv[4];
      const int c16 = (ks << 2) + fc;
#pragma unroll
      for (int i = 0; i < 4; ++i) {
        const int row = (w << 6) + (i << 4) + fr;
        af[i] = *(const bf16x8v*)(sG + row * BK + ((c16 ^ (row & 7)) << 3));
      }
#pragma unroll
      for (int j = 0; j < 4; ++j) {
        const int row = (j << 4) + fr;
        bfv[j] = *(const bf16x8v*)(sE + row * BK + ((c16 ^ (row & 7)) << 3));
      }
#pragma unroll
      for (int i = 0; i < 4; ++i)
#pragma unroll
        for (int j = 0; j < 4; ++j)
          acc[i][j] = mfma16(af[i], bfv[j], acc[i][j]);
    }
    __syncthreads();
  }

  // D layout: col(n=q)=lane&15, row(m=ic)=quad*4+reg -> packed 8B ushort4
  unsigned short* __restrict__ P =
      P16 + ((size_t)kc * BB + b) * HH * IC;
  const int quad = lane >> 4;
  const int col = lane & 15;
#pragma unroll
  for (int i = 0; i < 4; ++i) {
    const int ic0 = (w << 6) + (i << 4) + (quad << 2);
#pragma unroll
    for (int j = 0; j < 4; ++j) {
      const int q = qBase + (j << 4) + col;
      ushort4 s = {hbits(acc[i][j][0]), hbits(acc[i][j][1]),
                   hbits(acc[i][j][2]), hbits(acc[i][j][3])};
      *(ushort4*)(P + (size_t)q * IC + ic0) = s;
    }
  }
}

// x [B,C,H] fp32 -> xT [B,H,C] fp16. Round 9: also absorbs the old convw
// kernel — blockIdx.y == CC/64 slice converts the 4 weight tensors to fp16
// (blockIdx.z selects which; 64 blocks x 256 thr x 8 elems = 131072 each).
__launch_bounds__(256)
__global__ void xpose(const float* __restrict__ x, __half* __restrict__ xT,
                      const float* __restrict__ w0, const float* __restrict__ w1,
                      const float* __restrict__ w2, const float* __restrict__ w3,
                      __half* __restrict__ d0, __half* __restrict__ d1,
                      __half* __restrict__ d2, __half* __restrict__ d3) {
  if (blockIdx.y == CC / 64) {
    const int which = blockIdx.z;
    const float* s = which == 0 ? w0 : (which == 1 ? w1 : (which == 2 ? w2 : w3));
    __half* d = which == 0 ? d0 : (which == 1 ? d1 : (which == 2 ? d2 : d3));
    const int i = ((int)blockIdx.x * 256 + (int)threadIdx.x) * 8;
    const float4 v0 = *(const float4*)(s + i);
    const float4 v1 = *(const float4*)(s + i + 4);
    __half h[8] = {__float2half(v0.x), __float2half(v0.y), __float2half(v0.z),
                   __float2half(v0.w), __float2half(v1.x), __float2half(v1.y),
                   __float2half(v1.z), __float2half(v1.w)};
    uint4 pack; __builtin_memcpy(&pack, h, 16);
    *(uint4*)(d + i) = pack;
    return;
  }
  __shared__ float tile[64][65];
  const int b = blockIdx.z;
  const int h0 = blockIdx.x * 64;
  const int c0 = blockIdx.y * 64;
  const int lane = threadIdx.x & 63;
  const int r0 = threadIdx.x >> 6;
  const float* xb = x + (size_t)b * CC * HH;
#pragma unroll
  for (int rr = 0; rr < 16; ++rr) {
    const int c = r0 * 16 + rr;
    tile[c][lane] = xb[(size_t)(c0 + c) * HH + h0 + lane];
  }
  __syncthreads();
  __half* ob = xT + (size_t)b * HH * CC;
#pragma unroll
  for (int rr = 0; rr < 16; ++rr) {
    const int hl = r0 * 16 + rr;
    ob[(size_t)(h0 + hl) * CC + c0 + lane] = __float2half(tile[lane][hl]);
  }
}

// ---------------------------------------------------------------------------
extern "C" void kernel_launch(void* const* d_in, const int* in_sizes, int n_in,
                              void* d_out, int out_size, void* d_ws, size_t ws_size,
                              hipStream_t stream) {
  (void)in_sizes; (void)n_in; (void)out_size; (void)ws_size;

  const float* x       = (const float*)d_in[0];
  const float* w_phi   = (const float*)d_in[1];
  const float* b_phi   = (const float*)d_in[2];
  const float* w_theta = (const float*)d_in[3];
  const float* b_theta = (const float*)d_in[4];
  const float* w_g     = (const float*)d_in[5];
  const float* b_g     = (const float*)d_in[6];
  const float* w_mask  = (const float*)d_in[7];
  const float* b_mask  = (const float*)d_in[8];
  float* out = (float*)d_out;

  char* p = (char*)d_ws;
  __hip_bfloat16* E = (__hip_bfloat16*)p;           p += (size_t)BB * HH * HH * 2;   // [q][k]
  __half* xT       = (__half*)p;                    p += (size_t)BB * HH * CC * 2;   // 16.8 MB
  __half* thetaH   = (__half*)p;                    p += (size_t)BB * HH * IC * 2;   // [h][ic]
  __half* phiH     = (__half*)p;                    p += (size_t)BB * HH * IC * 2;   // [h][ic]
  __hip_bfloat16* gB  = (__hip_bfloat16*)p;         p += (size_t)BB * IC * HH * 2;   // [ic][h]
  __half* wthH = (__half*)p;                        p += (size_t)IC * CC * 2;
  __half* wphH = (__half*)p;                        p += (size_t)IC * CC * 2;
  __half* wgH  = (__half*)p;                        p += (size_t)IC * CC * 2;
  __half* wmH  = (__half*)p;                        p += (size_t)CC * IC * 2;
  float* Z = (float*)p;                             p += (size_t)BB * HH * 4;
  // fp16 split-K=2 partials (2 x 8.4 MB = 16.8 MB) alias xT exactly; xT is
  // dead by the time mgemm_ag runs. Consumed directly by mgemm128<3>.
  unsigned short* P16 = (unsigned short*)xT;

  const dim3 blk(256);

  // xpose (+ fused weight conversion in the extra y-slice)
  xpose<<<dim3(HH / 64, CC / 64 + 1, BB), blk, 0, stream>>>(
      x, xT, w_phi, w_theta, w_g, w_mask, wphH, wthH, wgH, wmH);

  hipMemsetAsync(Z, 0, (size_t)BB * HH * sizeof(float), stream);

  // theta/phi dual: A=xT [H,C], B=w_theta/w_phi [IC,C]; out [h][ic] fp16, +bias[ic]
  mgemm128<0, 64><<<dim3(IC / 128, HH / 128, BB * 2), blk, 0, stream>>>(
      xT, wthH, wphH, thetaH, phiH, b_theta, b_phi, nullptr, nullptr,
      HH, IC, CC, (size_t)HH * CC, 0, (size_t)HH * IC);

  // scores: A=theta (m=q), B=phi (n=k); E[q][k] bf16 + Z[b,k]
  mgemm128<2, 64><<<dim3(HH / 128, HH / 128, BB), blk, 0, stream>>>(
      thetaH, phiH, nullptr, E, nullptr, nullptr, nullptr, nullptr, Z,
      HH, HH, IC, (size_t)HH * IC, (size_t)HH * IC, (size_t)HH * HH);

  // g (AFTER scores so Z is ready): A=wg [IC,C], B=xT [H,C];
  // out gB[ic][h] bf16 = (v + bias[ic]) / Z[b,h]  (gscale fused)
  mgemm128<1, 64><<<dim3(HH / 128, IC / 128, BB), blk, 0, stream>>>(
      wgH, xT, nullptr, gB, nullptr, b_g, nullptr, nullptr, Z,
      IC, HH, CC, 0, (size_t)HH * CC, (size_t)IC * HH);

  // ag: BK=128 (256B-contiguous E reads), split-K=2, XOR-swizzled LDS
  mgemm_ag<<<dim3(2, HH / 64, BB), blk, 0, stream>>>(gB, E, P16);

  // final: A=wm [C,IC] fp16, B = P16 half0+half1 (fp16, reg-staged add);
  // out[c][h] fp32 + bias[c] + x
  mgemm128<3, 64><<<dim3(HH / 128, CC / 128, BB), blk, 0, stream>>>(
      wmH, P16, nullptr, out, nullptr, b_mask, nullptr, x, nullptr,
      CC, HH, IC, 0, (size_t)HH * IC, (size_t)CC * HH);
}

// Round 10
// 244.032 us; speedup vs baseline: 1.0391x; 1.0391x over previous
//
#include <hip/hip_runtime.h>
#include <hip/hip_bf16.h>
#include <hip/hip_fp16.h>
#include <type_traits>

constexpr int BB = 4;
constexpr int CC = 512;
constexpr int HH = 4096;
constexpr int IC = 256;

typedef _Float16 f16x8v __attribute__((ext_vector_type(8)));
typedef __bf16   bf16x8v __attribute__((ext_vector_type(8)));
typedef float    f32x4v __attribute__((ext_vector_type(4)));

__device__ __forceinline__ void gll16(const void* g, void* l) {
  __builtin_amdgcn_global_load_lds(
      (const __attribute__((address_space(1))) unsigned int*)g,
      (__attribute__((address_space(3))) unsigned int*)l, 16, 0, 0);
}

__device__ __forceinline__ f32x4v mfma16(f16x8v a, f16x8v b, f32x4v c) {
  return __builtin_amdgcn_mfma_f32_16x16x32_f16(a, b, c, 0, 0, 0);
}
__device__ __forceinline__ f32x4v mfma16(bf16x8v a, bf16x8v b, f32x4v c) {
  return __builtin_amdgcn_mfma_f32_16x16x32_bf16(a, b, c, 0, 0, 0);
}

__device__ __forceinline__ unsigned short hbits(float f) {
  __half h = __float2half(f);
  unsigned short b; __builtin_memcpy(&b, &h, 2); return b;
}
__device__ __forceinline__ unsigned short bbits(float f) {
  __hip_bfloat16 h = __float2bfloat16(f);
  unsigned short b; __builtin_memcpy(&b, &h, 2); return b;
}

// ---------------------------------------------------------------------------
// 128x128-tile B^T GEMM (ROUND-4 PROVEN core: BK=64 + chunk-XOR staging
// swizzle, bank conflicts 0, VGPR 80, LDS 32KB).
// Failed levers (do not retry): BK=128 (r5: occupancy halves), LDS-staged
// MODE2 epilogue (r6: adds issue work), no-LDS direct fragments (r7:
// scattered per-lane loads, 139us), swapped packed epilogue (r1: WRITE_SIZE
// +50%). Cross-round MODE2 timing variance is ~±10% at fixed code (r4 62.5
// vs r8 74.6, uniform counter dilution) — don't chase it.
// MODE 0: DUAL theta+phi (blockIdx.z>>2 selects B/bias/out). fp16, +bias[n].
// MODE 1: bf16, (v+bias[m])/Z[b,n]  (g proj -> gB [IC,H]; gscale fused,
//         runs AFTER MODE2 so Z is ready).
// MODE 2: bf16 exp(v); Z[b,n] += column sums   (scores -> E [q,k])
// MODE 3: fp32, +bias[m] + xres; B operand = SUM OF TWO fp16 SPLIT-K
//         PARTIALS (P16 halves) reg-staged with in-register add (r8 proven).
// ---------------------------------------------------------------------------
template <int MODE, int BK>
__launch_bounds__(256)
__global__ void mgemm128(const void* __restrict__ Aall, const void* __restrict__ Ball,
                         const void* __restrict__ Ball2,
                         void* __restrict__ outP, void* __restrict__ out2P,
                         const float* __restrict__ bias, const float* __restrict__ bias2,
                         const float* __restrict__ xres, float* __restrict__ Z,
                         int M, int N, int K,
                         size_t sAb, size_t sBb, size_t sOb) {
  constexpr int CPR = BK / 8;              // 16B chunks per LDS row
  constexpr int XM = (BK >= 64) ? 7 : 0;   // chunk-XOR swizzle mask

  __shared__ __align__(16) unsigned short sA[128 * BK];
  __shared__ __align__(16) unsigned short sB[128 * BK];

  const int zz = blockIdx.z;
  int b, which;
  if constexpr (MODE == 0) { b = zz & (BB - 1); which = zz >> 2; }
  else { b = zz; which = 0; }

  const unsigned short* __restrict__ A = (const unsigned short*)Aall + (size_t)b * sAb;
  const unsigned short* __restrict__ Bm =
      (const unsigned short*)((MODE == 0 && which) ? Ball2 : Ball) + (size_t)b * sBb;
  const float* __restrict__ biasSel = (MODE == 0 && which) ? bias2 : bias;
  void* __restrict__ outSel = (MODE == 0 && which) ? out2P : outP;

  const int t = threadIdx.x;
  const int lane = t & 63;
  const int w = t >> 6;
  const int wm = (w >> 1) << 6;
  const int wn = (w & 1) << 6;
  const int mBase = blockIdx.y * 128;
  const int nBase = blockIdx.x * 128;

  const int fr = lane & 15;
  const int fo = (lane >> 4) << 3;   // 0,8,16,24 shorts within the 32-k slice
  const int fc = fo >> 3;            // 16B sub-chunk index 0..3

  f32x4v acc[4][4] = {};

  for (int k0 = 0; k0 < K; k0 += BK) {
    // stage: 128 rows x BK k per operand = 128*CPR chunks; CPR/2 per thread
#pragma unroll
    for (int p = 0; p < CPR / 2; ++p) {
      const int u = t + (p << 8);
      const int r = u / CPR;
      const int c = u & (CPR - 1);
      const int cs = (c ^ (r & XM)) << 3;
      gll16(A + (size_t)(mBase + r) * K + (k0 + cs), sA + u * 8);
      if constexpr (MODE == 3) {
        // B = P16 half0 + half1 (fp16), reg-staged with vector add; LDS
        // layout identical to the gll16 path (linear dest, pre-XOR'd src).
        const unsigned short* s0 = Bm + (size_t)(nBase + r) * K + (k0 + cs);
        const f16x8v v0 = *(const f16x8v*)s0;
        const f16x8v v1 = *(const f16x8v*)(s0 + (size_t)BB * HH * IC);
        *(f16x8v*)(sB + u * 8) = v0 + v1;
      } else {
        gll16(Bm + (size_t)(nBase + r) * K + (k0 + cs), sB + u * 8);
      }
    }
    __syncthreads();
#pragma unroll
    for (int ks = 0; ks < BK / 32; ++ks) {
      f16x8v af[4], bf[4];
#pragma unroll
      for (int i = 0; i < 4; ++i) {
        const int row = wm + (i << 4) + fr;
        const int phys = ((ks << 2) + fc) ^ (row & XM);
        af[i] = *(const f16x8v*)(sA + row * BK + (phys << 3));
      }
#pragma unroll
      for (int j = 0; j < 4; ++j) {
        const int row = wn + (j << 4) + fr;
        const int phys = ((ks << 2) + fc) ^ (row & XM);
        bf[j] = *(const f16x8v*)(sB + row * BK + (phys << 3));
      }
#pragma unroll
      for (int i = 0; i < 4; ++i)
#pragma unroll
        for (int j = 0; j < 4; ++j)
          acc[i][j] = mfma16(af[i], bf[j], acc[i][j]);
    }
    __syncthreads();
  }

  const int row0 = (lane >> 4) << 2;
  const int col = lane & 15;

  if constexpr (MODE == 2) {
    __hip_bfloat16* __restrict__ outB = (__hip_bfloat16*)outP;
    float csum[4] = {0.f, 0.f, 0.f, 0.f};
#pragma unroll
    for (int i = 0; i < 4; ++i) {
      const int m0 = mBase + wm + (i << 4) + row0;
#pragma unroll
      for (int j = 0; j < 4; ++j) {
        const int n = nBase + wn + (j << 4) + col;
        __hip_bfloat16* dst = outB + (size_t)b * sOb + (size_t)m0 * N + n;
#pragma unroll
        for (int rg = 0; rg < 4; ++rg) {
          const float e = __expf(acc[i][j][rg]);
          dst[(size_t)rg * N] = __float2bfloat16(e);
          csum[j] += e;
        }
      }
    }
#pragma unroll
    for (int j = 0; j < 4; ++j) {
      float s = csum[j];
      s += __shfl_xor(s, 16, 64);
      s += __shfl_xor(s, 32, 64);
      if (lane < 16) {
        const int n = nBase + wn + (j << 4) + col;
        atomicAdd(&Z[(size_t)b * N + n], s);
      }
    }
  } else {
    // MODE1: per-column softmax-denominator reciprocal (n indep. of i/rg)
    float rzv[4];
    if constexpr (MODE == 1) {
#pragma unroll
      for (int j = 0; j < 4; ++j) {
        const int n = nBase + wn + (j << 4) + col;
        rzv[j] = 1.0f / Z[(size_t)b * N + n];
      }
    }
#pragma unroll
    for (int i = 0; i < 4; ++i) {
      const int m0 = mBase + wm + (i << 4) + row0;
#pragma unroll
      for (int j = 0; j < 4; ++j) {
        const int n = nBase + wn + (j << 4) + col;
#pragma unroll
        for (int rg = 0; rg < 4; ++rg) {
          const int m = m0 + rg;
          const float v = acc[i][j][rg];
          if constexpr (MODE == 0) {
            ((__half*)outSel)[(size_t)b * sOb + (size_t)m * N + n] =
                __float2half(v + biasSel[n]);
          } else if constexpr (MODE == 1) {
            ((__hip_bfloat16*)outP)[(size_t)b * sOb + (size_t)m * N + n] =
                __float2bfloat16((v + bias[m]) * rzv[j]);
          } else {
            const size_t o = (size_t)b * sOb + (size_t)m * N + n;
            ((float*)outP)[o] = v + bias[m] + xres[o];
          }
        }
      }
    }
  }
  (void)M;
}

// ---------------------------------------------------------------------------
// ag GEMM v4 (round 10). History: BK=32 72us (r0, DRAM-locality-bound —
// dbuf null, r2); BK=128 single-buffered ~45us (r3 PROVEN, 256B row visits).
// Now that locality is fixed, probe the remaining 2x gap over the ~22us
// floor as STAGE-DRAIN LATENCY: BK=64 (128B visits — proven adequate by all
// BK=64 mgemm128 kernels) + static-indexed double-buffer, 2 k-steps
// unrolled/iter. LDS 2*(32+8)KB = 80KB -> 2 blocks/CU (unchanged occupancy).
// Prefetch for step t+1 issues before compute of step t; the barrier still
// drains vmcnt(0), but loads complete under the 32-MFMA compute + sibling
// block's work. If this is null, ag is issue-bound at its floor.
// Partial tiles -> fp16 packed ushort4 stores into P16[kc][b][q][ic];
// consumed directly by mgemm128<3> (r8).
// ---------------------------------------------------------------------------
__launch_bounds__(256)
__global__ void mgemm_ag(const __hip_bfloat16* __restrict__ Gall,
                         const __hip_bfloat16* __restrict__ Eall,
                         unsigned short* __restrict__ P16) {
  constexpr int KC = 2048;
  constexpr int BK = 64;
  __shared__ __align__(16) unsigned short sG[2][256 * BK];  // 2 x 32 KB
  __shared__ __align__(16) unsigned short sE[2][64 * BK];   // 2 x 8 KB

  const int b = blockIdx.z;
  const int kc = blockIdx.x;            // 0..1
  const int qBase = blockIdx.y * 64;
  const int k0base = kc * KC;

  const unsigned short* __restrict__ G =
      (const unsigned short*)Gall + (size_t)b * IC * HH;
  const unsigned short* __restrict__ E =
      (const unsigned short*)Eall + (size_t)b * HH * HH;

  const int t = threadIdx.x;
  const int lane = t & 63;
  const int w = t >> 6;
  const int fr = lane & 15;
  const int fo = (lane >> 4) << 3;      // 0,8,16,24 shorts
  const int fc = fo >> 3;               // chunk sub-index 0..3

  f32x4v acc[4][4] = {};

  auto stage = [&](unsigned short* dG, unsigned short* dE, int k0) {
    // E first (HBM, long latency): 64 rows x 8 chunks = 512 -> 2/thread
#pragma unroll
    for (int p = 0; p < 2; ++p) {
      const int u = t + (p << 8);
      const int row = u >> 3;
      const int c = u & 7;
      gll16(E + (size_t)(qBase + row) * HH + k0 + ((c ^ (row & 7)) << 3),
            dE + u * 8);
    }
    // G (mostly L2): 256 rows x 8 chunks = 2048 -> 8/thread
#pragma unroll
    for (int p = 0; p < 8; ++p) {
      const int u = t + (p << 8);
      const int row = u >> 3;
      const int c = u & 7;
      gll16(G + (size_t)row * HH + k0 + ((c ^ (row & 7)) << 3), dG + u * 8);
    }
  };

  auto compute = [&](const unsigned short* pG, const unsigned short* pE) {
#pragma unroll
    for (int ks = 0; ks < 2; ++ks) {
      bf16x8v af[4], bfv[4];
      const int c16 = (ks << 2) + fc;
#pragma unroll
      for (int i = 0; i < 4; ++i) {
        const int row = (w << 6) + (i << 4) + fr;
        af[i] = *(const bf16x8v*)(pG + row * BK + ((c16 ^ (row & 7)) << 3));
      }
#pragma unroll
      for (int j = 0; j < 4; ++j) {
        const int row = (j << 4) + fr;
        bfv[j] = *(const bf16x8v*)(pE + row * BK + ((c16 ^ (row & 7)) << 3));
      }
#pragma unroll
      for (int i = 0; i < 4; ++i)
#pragma unroll
        for (int j = 0; j < 4; ++j)
          acc[i][j] = mfma16(af[i], bfv[j], acc[i][j]);
    }
  };

  stage(sG[0], sE[0], k0base);
  __syncthreads();
  for (int kk = 0; kk < KC; kk += 2 * BK) {
    stage(sG[1], sE[1], k0base + kk + BK);       // prefetch step t+1
    compute(sG[0], sE[0]);
    __syncthreads();
    if (kk + 2 * BK < KC)
      stage(sG[0], sE[0], k0base + kk + 2 * BK); // prefetch step t+2
    compute(sG[1], sE[1]);
    __syncthreads();
  }

  // D layout: col(n=q)=lane&15, row(m=ic)=quad*4+reg -> packed 8B ushort4
  unsigned short* __restrict__ P =
      P16 + ((size_t)kc * BB + b) * HH * IC;
  const int quad = lane >> 4;
  const int col = lane & 15;
#pragma unroll
  for (int i = 0; i < 4; ++i) {
    const int ic0 = (w << 6) + (i << 4) + (quad << 2);
#pragma unroll
    for (int j = 0; j < 4; ++j) {
      const int q = qBase + (j << 4) + col;
      ushort4 s = {hbits(acc[i][j][0]), hbits(acc[i][j][1]),
                   hbits(acc[i][j][2]), hbits(acc[i][j][3])};
      *(ushort4*)(P + (size_t)q * IC + ic0) = s;
    }
  }
}

// x [B,C,H] fp32 -> xT [B,H,C] fp16; blockIdx.y == CC/64 slice converts the
// 4 weight tensors to fp16 (blockIdx.z selects which).
__launch_bounds__(256)
__global__ void xpose(const float* __restrict__ x, __half* __restrict__ xT,
                      const float* __restrict__ w0, const float* __restrict__ w1,
                      const float* __restrict__ w2, const float* __restrict__ w3,
                      __half* __restrict__ d0, __half* __restrict__ d1,
                      __half* __restrict__ d2, __half* __restrict__ d3) {
  if (blockIdx.y == CC / 64) {
    const int which = blockIdx.z;
    const float* s = which == 0 ? w0 : (which == 1 ? w1 : (which == 2 ? w2 : w3));
    __half* d = which == 0 ? d0 : (which == 1 ? d1 : (which == 2 ? d2 : d3));
    const int i = ((int)blockIdx.x * 256 + (int)threadIdx.x) * 8;
    const float4 v0 = *(const float4*)(s + i);
    const float4 v1 = *(const float4*)(s + i + 4);
    __half h[8] = {__float2half(v0.x), __float2half(v0.y), __float2half(v0.z),
                   __float2half(v0.w), __float2half(v1.x), __float2half(v1.y),
                   __float2half(v1.z), __float2half(v1.w)};
    uint4 pack; __builtin_memcpy(&pack, h, 16);
    *(uint4*)(d + i) = pack;
    return;
  }
  __shared__ float tile[64][65];
  const int b = blockIdx.z;
  const int h0 = blockIdx.x * 64;
  const int c0 = blockIdx.y * 64;
  const int lane = threadIdx.x & 63;
  const int r0 = threadIdx.x >> 6;
  const float* xb = x + (size_t)b * CC * HH;
#pragma unroll
  for (int rr = 0; rr < 16; ++rr) {
    const int c = r0 * 16 + rr;
    tile[c][lane] = xb[(size_t)(c0 + c) * HH + h0 + lane];
  }
  __syncthreads();
  __half* ob = xT + (size_t)b * HH * CC;
#pragma unroll
  for (int rr = 0; rr < 16; ++rr) {
    const int hl = r0 * 16 + rr;
    ob[(size_t)(h0 + hl) * CC + c0 + lane] = __float2half(tile[lane][hl]);
  }
}

// ---------------------------------------------------------------------------
extern "C" void kernel_launch(void* const* d_in, const int* in_sizes, int n_in,
                              void* d_out, int out_size, void* d_ws, size_t ws_size,
                              hipStream_t stream) {
  (void)in_sizes; (void)n_in; (void)out_size; (void)ws_size;

  const float* x       = (const float*)d_in[0];
  const float* w_phi   = (const float*)d_in[1];
  const float* b_phi   = (const float*)d_in[2];
  const float* w_theta = (const float*)d_in[3];
  const float* b_theta = (const float*)d_in[4];
  const float* w_g     = (const float*)d_in[5];
  const float* b_g     = (const float*)d_in[6];
  const float* w_mask  = (const float*)d_in[7];
  const float* b_mask  = (const float*)d_in[8];
  float* out = (float*)d_out;

  char* p = (char*)d_ws;
  __hip_bfloat16* E = (__hip_bfloat16*)p;           p += (size_t)BB * HH * HH * 2;   // [q][k]
  __half* xT       = (__half*)p;                    p += (size_t)BB * HH * CC * 2;   // 16.8 MB
  __half* thetaH   = (__half*)p;                    p += (size_t)BB * HH * IC * 2;   // [h][ic]
  __half* phiH     = (__half*)p;                    p += (size_t)BB * HH * IC * 2;   // [h][ic]
  __hip_bfloat16* gB  = (__hip_bfloat16*)p;         p += (size_t)BB * IC * HH * 2;   // [ic][h]
  __half* wthH = (__half*)p;                        p += (size_t)IC * CC * 2;
  __half* wphH = (__half*)p;                        p += (size_t)IC * CC * 2;
  __half* wgH  = (__half*)p;                        p += (size_t)IC * CC * 2;
  __half* wmH  = (__half*)p;                        p += (size_t)CC * IC * 2;
  float* Z = (float*)p;                             p += (size_t)BB * HH * 4;
  // fp16 split-K=2 partials (2 x 8.4 MB = 16.8 MB) alias xT exactly; xT is
  // dead by the time mgemm_ag runs. Consumed directly by mgemm128<3>.
  unsigned short* P16 = (unsigned short*)xT;

  const dim3 blk(256);

  // xpose (+ fused weight conversion in the extra y-slice)
  xpose<<<dim3(HH / 64, CC / 64 + 1, BB), blk, 0, stream>>>(
      x, xT, w_phi, w_theta, w_g, w_mask, wphH, wthH, wgH, wmH);

  hipMemsetAsync(Z, 0, (size_t)BB * HH * sizeof(float), stream);

  // theta/phi dual: A=xT [H,C], B=w_theta/w_phi [IC,C]; out [h][ic] fp16, +bias[ic]
  mgemm128<0, 64><<<dim3(IC / 128, HH / 128, BB * 2), blk, 0, stream>>>(
      xT, wthH, wphH, thetaH, phiH, b_theta, b_phi, nullptr, nullptr,
      HH, IC, CC, (size_t)HH * CC, 0, (size_t)HH * IC);

  // scores: A=theta (m=q), B=phi (n=k); E[q][k] bf16 + Z[b,k]
  mgemm128<2, 64><<<dim3(HH / 128, HH / 128, BB), blk, 0, stream>>>(
      thetaH, phiH, nullptr, E, nullptr, nullptr, nullptr, nullptr, Z,
      HH, HH, IC, (size_t)HH * IC, (size_t)HH * IC, (size_t)HH * HH);

  // g (AFTER scores so Z is ready): A=wg [IC,C], B=xT [H,C];
  // out gB[ic][h] bf16 = (v + bias[ic]) / Z[b,h]  (gscale fused)
  mgemm128<1, 64><<<dim3(HH / 128, IC / 128, BB), blk, 0, stream>>>(
      wgH, xT, nullptr, gB, nullptr, b_g, nullptr, nullptr, Z,
      IC, HH, CC, 0, (size_t)HH * CC, (size_t)IC * HH);

  // ag: BK=64 static-dbuf prefetch (r10 probe), split-K=2, XOR-swizzled LDS
  mgemm_ag<<<dim3(2, HH / 64, BB), blk, 0, stream>>>(gB, E, P16);

  // final: A=wm [C,IC] fp16, B = P16 half0+half1 (fp16, reg-staged add);
  // out[c][h] fp32 + bias[c] + x
  mgemm128<3, 64><<<dim3(HH / 128, CC / 128, BB), blk, 0, stream>>>(
      wmH, P16, nullptr, out, nullptr, b_mask, nullptr, x, nullptr,
      CC, HH, IC, 0, (size_t)HH * IC, (size_t)CC * HH);
}